// Round 1
// baseline (336.963 us; speedup 1.0000x reference)
//
#include <hip/hip_runtime.h>
#include <stdint.h>

#define M_TOK 32768
#define N_OUT 1024
#define K_IN  1024

#define BM 128
#define BN 128
#define BK 32

typedef __bf16 bf16_t;
typedef bf16_t bf16x8 __attribute__((ext_vector_type(8)));
typedef float  floatx4 __attribute__((ext_vector_type(4)));

__device__ __forceinline__ unsigned short f2bf(float f) {
    // round-to-nearest-even fp32 -> bf16
    uint32_t u = __float_as_uint(f);
    u += 0x7FFFu + ((u >> 16) & 1u);
    return (unsigned short)(u >> 16);
}

// x fp32 -> bf16, 8 elements per thread, exact sizing (no bounds check needed)
__global__ void cvt_x_kernel(const float* __restrict__ x, unsigned short* __restrict__ xb) {
    size_t i = (size_t)blockIdx.x * blockDim.x + threadIdx.x;   // group of 8 floats
    const float4* xv = (const float4*)(x + i * 8);
    float4 a = xv[0];
    float4 b = xv[1];
    unsigned int p0 = (unsigned int)f2bf(a.x) | ((unsigned int)f2bf(a.y) << 16);
    unsigned int p1 = (unsigned int)f2bf(a.z) | ((unsigned int)f2bf(a.w) << 16);
    unsigned int p2 = (unsigned int)f2bf(b.x) | ((unsigned int)f2bf(b.y) << 16);
    unsigned int p3 = (unsigned int)f2bf(b.z) | ((unsigned int)f2bf(b.w) << 16);
    uint4 o; o.x = p0; o.y = p1; o.z = p2; o.w = p3;
    *(uint4*)(xb + i * 8) = o;
}

// sign(w) -> bf16 {+1,-1,0}, 4 elements per thread
__global__ void cvt_w_kernel(const float* __restrict__ w, unsigned short* __restrict__ wb) {
    size_t i = (size_t)blockIdx.x * blockDim.x + threadIdx.x;   // group of 4
    const float4* wv = (const float4*)(w + i * 4);
    float4 a = wv[0];
    unsigned short s0 = (a.x > 0.f) ? 0x3F80u : ((a.x < 0.f) ? 0xBF80u : 0u);
    unsigned short s1 = (a.y > 0.f) ? 0x3F80u : ((a.y < 0.f) ? 0xBF80u : 0u);
    unsigned short s2 = (a.z > 0.f) ? 0x3F80u : ((a.z < 0.f) ? 0xBF80u : 0u);
    unsigned short s3 = (a.w > 0.f) ? 0x3F80u : ((a.w < 0.f) ? 0xBF80u : 0u);
    uint2 o;
    o.x = (unsigned int)s0 | ((unsigned int)s1 << 16);
    o.y = (unsigned int)s2 | ((unsigned int)s3 << 16);
    *(uint2*)(wb + i * 4) = o;
}

// C[M][N] = A[M][K] * B[N][K]^T + bias, A/B bf16, C fp32.
// 256 threads = 4 waves, each wave does a 64x64 sub-tile as 4x4 MFMA 16x16x32.
__global__ __launch_bounds__(256) void gemm_sign_kernel(
    const unsigned short* __restrict__ A,   // [M][K] bf16 bits
    const unsigned short* __restrict__ B,   // [N][K] bf16 bits (= sign(W), W layout)
    const float* __restrict__ bias,         // [N]
    float* __restrict__ C)                  // [M][N]
{
    __shared__ __align__(16) unsigned short sA[BM * BK];
    __shared__ __align__(16) unsigned short sB[BN * BK];

    const int t    = threadIdx.x;
    const int bn   = blockIdx.x;      // 0..7
    const int bm   = blockIdx.y;      // 0..255
    const int wave = t >> 6;
    const int lane = t & 63;
    const int wm   = wave >> 1;       // 0..1
    const int wn   = wave & 1;        // 0..1
    const int lrow = lane & 15;       // m (A) / n (B) / col (C)
    const int quad = lane >> 4;       // 0..3

    // staging indices: each thread moves 2x16B for A and 2x16B for B per k-tile
    const int row0 = t >> 2;          // 0..63
    const int col0 = (t & 3) * 8;     // 0,8,16,24 (bf16 elements)

    const size_t a_base0 = (size_t)(bm * BM + row0) * K_IN + col0;
    const size_t a_base1 = (size_t)(bm * BM + 64 + row0) * K_IN + col0;
    const size_t b_base0 = (size_t)(bn * BN + row0) * K_IN + col0;
    const size_t b_base1 = (size_t)(bn * BN + 64 + row0) * K_IN + col0;

    floatx4 acc[4][4] = {};

    for (int kt = 0; kt < K_IN / BK; ++kt) {
        const int kbase = kt * BK;
        uint4 a0 = *(const uint4*)(A + a_base0 + kbase);
        uint4 a1 = *(const uint4*)(A + a_base1 + kbase);
        uint4 b0 = *(const uint4*)(B + b_base0 + kbase);
        uint4 b1 = *(const uint4*)(B + b_base1 + kbase);

        __syncthreads();   // previous iteration's LDS reads complete
        *(uint4*)(sA + row0 * BK + col0)        = a0;
        *(uint4*)(sA + (64 + row0) * BK + col0) = a1;
        *(uint4*)(sB + row0 * BK + col0)        = b0;
        *(uint4*)(sB + (64 + row0) * BK + col0) = b1;
        __syncthreads();

        bf16x8 af[4], bfr[4];
#pragma unroll
        for (int i = 0; i < 4; ++i)
            af[i] = *(const bf16x8*)(sA + (wm * 64 + i * 16 + lrow) * BK + quad * 8);
#pragma unroll
        for (int j = 0; j < 4; ++j)
            bfr[j] = *(const bf16x8*)(sB + (wn * 64 + j * 16 + lrow) * BK + quad * 8);

#pragma unroll
        for (int i = 0; i < 4; ++i)
#pragma unroll
            for (int j = 0; j < 4; ++j)
                acc[i][j] = __builtin_amdgcn_mfma_f32_16x16x32_bf16(af[i], bfr[j], acc[i][j], 0, 0, 0);
    }

    // epilogue: C[row][col] = acc + bias[col]
    const int crow_base = bm * BM + wm * 64;
    const int ccol_base = bn * BN + wn * 64;
#pragma unroll
    for (int j = 0; j < 4; ++j) {
        const int col = ccol_base + j * 16 + lrow;
        const float bv = bias[col];
#pragma unroll
        for (int i = 0; i < 4; ++i) {
            const int rbase = crow_base + i * 16 + quad * 4;
#pragma unroll
            for (int r = 0; r < 4; ++r) {
                C[(size_t)(rbase + r) * N_OUT + col] = acc[i][j][r] + bv;
            }
        }
    }
}

extern "C" void kernel_launch(void* const* d_in, const int* in_sizes, int n_in,
                              void* d_out, int out_size, void* d_ws, size_t ws_size,
                              hipStream_t stream) {
    const float* x    = (const float*)d_in[0];   // [32768,1024]
    const float* w    = (const float*)d_in[1];   // [1024,1024]
    const float* bias = (const float*)d_in[2];   // [1024]
    float* out        = (float*)d_out;           // [32768,1024]

    unsigned short* xb = (unsigned short*)d_ws;                       // 64 MB
    unsigned short* wb = (unsigned short*)((char*)d_ws + (size_t)M_TOK * K_IN * 2);  // 2 MB

    // x: 33554432 elements / 8 per thread = 4194304 threads = 16384 blocks x 256
    cvt_x_kernel<<<16384, 256, 0, stream>>>(x, xb);
    // w: 1048576 elements / 4 per thread = 262144 threads = 1024 blocks x 256
    cvt_w_kernel<<<1024, 256, 0, stream>>>(w, wb);

    dim3 grid(N_OUT / BN, M_TOK / BM);   // (8, 256)
    gemm_sign_kernel<<<grid, 256, 0, stream>>>(xb, wb, bias, out);
}

// Round 2
// 306.816 us; speedup vs baseline: 1.0983x; 1.0983x over previous
//
#include <hip/hip_runtime.h>
#include <stdint.h>

#define M_TOK 32768
#define N_OUT 1024
#define K_IN  1024

#define BM 128
#define BN 128
#define BK 32

typedef __bf16 bf16_t;
typedef bf16_t bf16x8 __attribute__((ext_vector_type(8)));
typedef float  floatx4 __attribute__((ext_vector_type(4)));

__device__ __forceinline__ unsigned short f2bf(float f) {
    // round-to-nearest-even fp32 -> bf16
    uint32_t u = __float_as_uint(f);
    u += 0x7FFFu + ((u >> 16) & 1u);
    return (unsigned short)(u >> 16);
}

// x fp32 -> bf16, 8 elements per thread
__global__ void cvt_x_kernel(const float* __restrict__ x, unsigned short* __restrict__ xb) {
    size_t i = (size_t)blockIdx.x * blockDim.x + threadIdx.x;   // group of 8 floats
    const float4* xv = (const float4*)(x + i * 8);
    float4 a = xv[0];
    float4 b = xv[1];
    unsigned int p0 = (unsigned int)f2bf(a.x) | ((unsigned int)f2bf(a.y) << 16);
    unsigned int p1 = (unsigned int)f2bf(a.z) | ((unsigned int)f2bf(a.w) << 16);
    unsigned int p2 = (unsigned int)f2bf(b.x) | ((unsigned int)f2bf(b.y) << 16);
    unsigned int p3 = (unsigned int)f2bf(b.z) | ((unsigned int)f2bf(b.w) << 16);
    uint4 o; o.x = p0; o.y = p1; o.z = p2; o.w = p3;
    *(uint4*)(xb + i * 8) = o;
}

// sign(w) -> bf16 {+1,-1,0}, 4 elements per thread
__global__ void cvt_w_kernel(const float* __restrict__ w, unsigned short* __restrict__ wb) {
    size_t i = (size_t)blockIdx.x * blockDim.x + threadIdx.x;   // group of 4
    const float4* wv = (const float4*)(w + i * 4);
    float4 a = wv[0];
    unsigned short s0 = (a.x > 0.f) ? 0x3F80u : ((a.x < 0.f) ? 0xBF80u : 0u);
    unsigned short s1 = (a.y > 0.f) ? 0x3F80u : ((a.y < 0.f) ? 0xBF80u : 0u);
    unsigned short s2 = (a.z > 0.f) ? 0x3F80u : ((a.z < 0.f) ? 0xBF80u : 0u);
    unsigned short s3 = (a.w > 0.f) ? 0x3F80u : ((a.w < 0.f) ? 0xBF80u : 0u);
    uint2 o;
    o.x = (unsigned int)s0 | ((unsigned int)s1 << 16);
    o.y = (unsigned int)s2 | ((unsigned int)s3 << 16);
    *(uint2*)(wb + i * 4) = o;
}

// async 16B global -> LDS (direct, no VGPR round trip)
__device__ __forceinline__ void stage16(const unsigned short* gsrc, unsigned short* ldst) {
    __builtin_amdgcn_global_load_lds(
        (const __attribute__((address_space(1))) unsigned int*)gsrc,
        (__attribute__((address_space(3))) unsigned int*)ldst,
        16, 0, 0);
}

// C[M][N] = A[M][K] * B[N][K]^T + bias, A/B bf16, C fp32.
// 256 threads = 4 waves; wave does 64x64 sub-tile as 4x4 MFMA 16x16x32.
// m97-style: global_load_lds width-16 staging, single LDS buffer, 2 barriers/iter.
__global__ __launch_bounds__(256) void gemm_sign_kernel(
    const unsigned short* __restrict__ A,   // [M][K] bf16 bits
    const unsigned short* __restrict__ B,   // [N][K] bf16 bits (= sign(W))
    const float* __restrict__ bias,         // [N]
    float* __restrict__ C)                  // [M][N]
{
    __shared__ __align__(16) unsigned short sA[BM * BK];   // 8 KB, row-major [128][32], NO padding
    __shared__ __align__(16) unsigned short sB[BN * BK];   // 8 KB

    const int t    = threadIdx.x;
    // XCD-aware swizzle: empirically XCD = linear_block_id % 8 (round-robin).
    // bm = (b>>6)*8 + (b&7): each XCD walks one bm strip through all 8 bn
    // values back-to-back -> A strip (256 KB) stays resident in that XCD's L2.
    const int b    = blockIdx.x;
    const int bm   = ((b >> 6) << 3) + (b & 7);   // 0..255
    const int bn   = (b >> 3) & 7;                // 0..7

    const int wave = t >> 6;
    const int lane = t & 63;
    const int wm   = wave >> 1;       // 0..1
    const int wn   = wave & 1;        // 0..1
    const int lrow = lane & 15;       // m (A) / n (B) / col (C)
    const int quad = lane >> 4;       // 0..3

    // Staging geometry: one global_load_lds(16B) per lane covers 1 KB/wave.
    // Wave w, call q in {0,1}: LDS short-offset = w*1024 + q*512 + lane*8
    //   -> row = w*32 + q*16 + lane/4, col = (lane&3)*8  (row stride 32 shorts)
    const int srow = (wave << 5) + (lane >> 2);   // + q*16
    const int scol = (lane & 3) << 3;
    const int lds_off = (t << 3);                 // w*1024*... == t*8 for q=0 chunk? no:
    // careful: w*1024 + lane*8 == (wave*128 + lane)*8 == t*8 only if wave stride were 512.
    // w*1024 + q*512 + lane*8; compute explicitly below.

    unsigned short* sA0 = sA + wave * 1024 + lane * 8;          // q=0
    unsigned short* sA1 = sA + wave * 1024 + 512 + lane * 8;    // q=1
    unsigned short* sB0 = sB + wave * 1024 + lane * 8;
    unsigned short* sB1 = sB + wave * 1024 + 512 + lane * 8;

    const unsigned short* gA0 = A + (size_t)(bm * BM + srow)      * K_IN + scol;
    const unsigned short* gA1 = A + (size_t)(bm * BM + srow + 16) * K_IN + scol;
    const unsigned short* gB0 = B + (size_t)(bn * BN + srow)      * K_IN + scol;
    const unsigned short* gB1 = B + (size_t)(bn * BN + srow + 16) * K_IN + scol;

    floatx4 acc[4][4] = {};

    for (int kt = 0; kt < K_IN / BK; ++kt) {
        const int kbase = kt * BK;
        __syncthreads();   // all waves done reading LDS from previous iter
        stage16(gA0 + kbase, sA0);
        stage16(gA1 + kbase, sA1);
        stage16(gB0 + kbase, sB0);
        stage16(gB1 + kbase, sB1);
        __syncthreads();   // vmcnt(0) drain + barrier: staging landed

        bf16x8 af[4], bfr[4];
#pragma unroll
        for (int i = 0; i < 4; ++i)
            af[i] = *(const bf16x8*)(sA + (wm * 64 + i * 16 + lrow) * BK + quad * 8);
#pragma unroll
        for (int j = 0; j < 4; ++j)
            bfr[j] = *(const bf16x8*)(sB + (wn * 64 + j * 16 + lrow) * BK + quad * 8);

#pragma unroll
        for (int i = 0; i < 4; ++i)
#pragma unroll
            for (int j = 0; j < 4; ++j)
                acc[i][j] = __builtin_amdgcn_mfma_f32_16x16x32_bf16(af[i], bfr[j], acc[i][j], 0, 0, 0);
    }

    // epilogue: C[row][col] = acc + bias[col]
    const int crow_base = bm * BM + wm * 64;
    const int ccol_base = bn * BN + wn * 64;
#pragma unroll
    for (int j = 0; j < 4; ++j) {
        const int col = ccol_base + j * 16 + lrow;
        const float bv = bias[col];
#pragma unroll
        for (int i = 0; i < 4; ++i) {
            const int rbase = crow_base + i * 16 + quad * 4;
#pragma unroll
            for (int r = 0; r < 4; ++r) {
                C[(size_t)(rbase + r) * N_OUT + col] = acc[i][j][r] + bv;
            }
        }
    }
}

extern "C" void kernel_launch(void* const* d_in, const int* in_sizes, int n_in,
                              void* d_out, int out_size, void* d_ws, size_t ws_size,
                              hipStream_t stream) {
    const float* x    = (const float*)d_in[0];   // [32768,1024]
    const float* w    = (const float*)d_in[1];   // [1024,1024]
    const float* bias = (const float*)d_in[2];   // [1024]
    float* out        = (float*)d_out;           // [32768,1024]

    unsigned short* xb = (unsigned short*)d_ws;                                      // 64 MB
    unsigned short* wb = (unsigned short*)((char*)d_ws + (size_t)M_TOK * K_IN * 2);  // 2 MB

    cvt_x_kernel<<<16384, 256, 0, stream>>>(x, xb);
    cvt_w_kernel<<<1024, 256, 0, stream>>>(w, wb);

    gemm_sign_kernel<<<(M_TOK / BM) * (N_OUT / BN), 256, 0, stream>>>(xb, wb, bias, out);
}